// Round 2
// baseline (751.599 us; speedup 1.0000x reference)
//
#include <hip/hip_runtime.h>
#include <cstddef>
#include <cstdint>

// ---------------- problem constants ----------------
#define ALPHA_C 7.7550531393693407f   // -log(0.001/7*3)
constexpr int BB = 2;      // batch
constexpr int LL = 2048;   // seq len
constexpr int DD = 512;    // d_model
constexpr int HH = 8;      // heads
constexpr size_t OUT0     = (size_t)BB * LL * DD;        // 2,097,152 floats (output 0)
constexpr size_t QH_ELEMS = (size_t)BB * HH * LL * 64;   // 2,097,152 floats per projection

typedef __attribute__((ext_vector_type(8))) short bf16x8;
typedef __attribute__((ext_vector_type(4))) float f32x4;

__device__ inline short f2bf(float x) {
  union { float f; unsigned u; } un; un.f = x;
  unsigned r = un.u + 0x7fffu + ((un.u >> 16) & 1u);   // RNE truncate to bf16
  return (short)(r >> 16);
}
__device__ inline float bf2f(short s) {
  union { unsigned u; float f; } un; un.u = ((unsigned)(unsigned short)s) << 16;
  return un.f;
}
// 3-way bf16 split: x ~= h + m + l, captures ~24 mantissa bits
__device__ inline void split3(float x, short& h, short& m, short& l) {
  h = f2bf(x); float r = x - bf2f(h);
  m = f2bf(r); float r2 = r - bf2f(m);
  l = f2bf(r2);
}
__device__ inline unsigned pack2(short a, short b) {
  return (unsigned)(unsigned short)a | ((unsigned)(unsigned short)b << 16);
}

// ---------------- K1: fused QKV projection (fp32 SGEMM) ----------------
// grid (24, 64): x -> {q,k,v} x 8 n-tiles of 64; y -> m-tile of 64 (M = B*L = 4096)
__global__ __launch_bounds__(256) void k_proj(
    const float* __restrict__ q, const float* __restrict__ k, const float* __restrict__ v,
    const float* __restrict__ wq, const float* __restrict__ wk, const float* __restrict__ wv,
    float* __restrict__ qh, float* __restrict__ kh, float* __restrict__ vh)
{
  const int bx  = blockIdx.x;
  const int sel = bx >> 3;                 // 0=q,1=k,2=v
  const int n0  = (bx & 7) * 64;
  const int m0  = blockIdx.y * 64;
  const float* X = sel == 0 ? q  : (sel == 1 ? k  : v);
  const float* W = sel == 0 ? wq : (sel == 1 ? wk : wv);
  float*       Y = sel == 0 ? qh : (sel == 1 ? kh : vh);

  __shared__ float As[32][68];
  __shared__ float Bs[32][68];
  const int tid = threadIdx.x;
  const int tr = tid >> 4, tc = tid & 15;
  const int lm = tid >> 2, lk0 = tid & 3;

  float acc[4][4] = {};
  for (int k0 = 0; k0 < 512; k0 += 32) {
    #pragma unroll
    for (int it = 0; it < 2; ++it) {
      int kv = lk0 + 4 * it;
      float4 a = *(const float4*)&X[(size_t)(m0 + lm) * 512 + k0 + kv * 4];
      As[kv*4+0][lm] = a.x; As[kv*4+1][lm] = a.y; As[kv*4+2][lm] = a.z; As[kv*4+3][lm] = a.w;
      float4 b = *(const float4*)&W[(size_t)(n0 + lm) * 512 + k0 + kv * 4];
      Bs[kv*4+0][lm] = b.x; Bs[kv*4+1][lm] = b.y; Bs[kv*4+2][lm] = b.z; Bs[kv*4+3][lm] = b.w;
    }
    __syncthreads();
    #pragma unroll 8
    for (int kk = 0; kk < 32; ++kk) {
      float4 av = *(const float4*)&As[kk][tr * 4];
      float4 bv = *(const float4*)&Bs[kk][tc * 4];
      acc[0][0] += av.x*bv.x; acc[0][1] += av.x*bv.y; acc[0][2] += av.x*bv.z; acc[0][3] += av.x*bv.w;
      acc[1][0] += av.y*bv.x; acc[1][1] += av.y*bv.y; acc[1][2] += av.y*bv.z; acc[1][3] += av.y*bv.w;
      acc[2][0] += av.z*bv.x; acc[2][1] += av.z*bv.y; acc[2][2] += av.z*bv.z; acc[2][3] += av.z*bv.w;
      acc[3][0] += av.w*bv.x; acc[3][1] += av.w*bv.y; acc[3][2] += av.w*bv.z; acc[3][3] += av.w*bv.w;
    }
    __syncthreads();
  }
  const int e = n0 + tc * 4;
  const int h = e >> 6, dk = e & 63;
  #pragma unroll
  for (int r = 0; r < 4; ++r) {
    int m = m0 + tr * 4 + r;
    int b = m >> 11, l = m & 2047;
    float4 o; o.x = acc[r][0]; o.y = acc[r][1]; o.z = acc[r][2]; o.w = acc[r][3];
    *(float4*)&Y[((size_t)(b * HH + h) * LL + l) * 64 + dk] = o;
  }
}

// ---------------- K2: logits via 3-way-bf16-split MFMA + per-tile softmax stats ------
// grid (32 jt, 32 it, 16 bh), 256 thr. eld = -alpha*(j-i)*(q.k/8), fp32-equivalent
// precision via 6-term bilinear expansion hh+hm+mh+hl+lh+mm. Writes eld to the pooled
// region of d_out (scratch) and per-(row,jtile) (max, sumexp) to `stats`.
__global__ __launch_bounds__(256) void k_qk(
    const float* __restrict__ qh, const float* __restrict__ kh,
    float* __restrict__ eldout, float* __restrict__ stats)
{
  const int j0 = blockIdx.x * 64;
  const int i0 = blockIdx.y * 64;
  const int jt = blockIdx.x;
  const int bh = blockIdx.z;
  const float* Qb = qh + (size_t)bh * LL * 64;
  const float* Kb = kh + (size_t)bh * LL * 64;
  float*       Ob = eldout + (size_t)bh * LL * LL;

  __shared__ short Ah[64*64], Am[64*64], Al[64*64];
  __shared__ short Bh[64*64], Bm[64*64], Bl[64*64];

  const int tid = threadIdx.x;
  const int lane = tid & 63, w = tid >> 6;

  // stage + split both 64x64 fp32 tiles into 3 bf16 LDS planes each
  const int srow = tid >> 2, sc4 = tid & 3;
  #pragma unroll
  for (int it = 0; it < 4; ++it) {
    int kb = sc4 * 16 + it * 4;
    float4 a = *(const float4*)&Qb[(size_t)(i0 + srow) * 64 + kb];
    short h0,m0_,l0,h1,m1,l1,h2,m2,l2,h3,m3,l3;
    split3(a.x, h0, m0_, l0); split3(a.y, h1, m1, l1);
    split3(a.z, h2, m2, l2); split3(a.w, h3, m3, l3);
    int base = srow * 64 + kb;
    *(unsigned*)&Ah[base]   = pack2(h0, h1);  *(unsigned*)&Ah[base+2] = pack2(h2, h3);
    *(unsigned*)&Am[base]   = pack2(m0_, m1); *(unsigned*)&Am[base+2] = pack2(m2, m3);
    *(unsigned*)&Al[base]   = pack2(l0, l1);  *(unsigned*)&Al[base+2] = pack2(l2, l3);
    float4 b = *(const float4*)&Kb[(size_t)(j0 + srow) * 64 + kb];
    split3(b.x, h0, m0_, l0); split3(b.y, h1, m1, l1);
    split3(b.z, h2, m2, l2); split3(b.w, h3, m3, l3);
    *(unsigned*)&Bh[base]   = pack2(h0, h1);  *(unsigned*)&Bh[base+2] = pack2(h2, h3);
    *(unsigned*)&Bm[base]   = pack2(m0_, m1); *(unsigned*)&Bm[base+2] = pack2(m2, m3);
    *(unsigned*)&Bl[base]   = pack2(l0, l1);  *(unsigned*)&Bl[base+2] = pack2(l2, l3);
  }
  __syncthreads();

  f32x4 acc[4];
  #pragma unroll
  for (int t = 0; t < 4; ++t) { acc[t][0]=0.f; acc[t][1]=0.f; acc[t][2]=0.f; acc[t][3]=0.f; }

  #pragma unroll
  for (int ch = 0; ch < 2; ++ch) {
    const int ka = ((lane >> 4) << 3) + ch * 32;
    const int ar = (w * 16 + (lane & 15)) * 64 + ka;
    bf16x8 ah = *(const bf16x8*)&Ah[ar];
    bf16x8 am = *(const bf16x8*)&Am[ar];
    bf16x8 al = *(const bf16x8*)&Al[ar];
    #pragma unroll
    for (int t = 0; t < 4; ++t) {
      const int br = (t * 16 + (lane & 15)) * 64 + ka;
      bf16x8 bh_ = *(const bf16x8*)&Bh[br];
      bf16x8 bm_ = *(const bf16x8*)&Bm[br];
      bf16x8 bl_ = *(const bf16x8*)&Bl[br];
      acc[t] = __builtin_amdgcn_mfma_f32_16x16x32_bf16(ah, bh_, acc[t], 0, 0, 0);
      acc[t] = __builtin_amdgcn_mfma_f32_16x16x32_bf16(ah, bm_, acc[t], 0, 0, 0);
      acc[t] = __builtin_amdgcn_mfma_f32_16x16x32_bf16(am, bh_, acc[t], 0, 0, 0);
      acc[t] = __builtin_amdgcn_mfma_f32_16x16x32_bf16(ah, bl_, acc[t], 0, 0, 0);
      acc[t] = __builtin_amdgcn_mfma_f32_16x16x32_bf16(al, bh_, acc[t], 0, 0, 0);
      acc[t] = __builtin_amdgcn_mfma_f32_16x16x32_bf16(am, bm_, acc[t], 0, 0, 0);
    }
  }

  // epilogue: eld, store, per-tile (max, sumexp) via 16-lane shuffles
  const int quad = lane >> 4, colg = lane & 15;
  float eld[4][4];
  #pragma unroll
  for (int t = 0; t < 4; ++t)
    #pragma unroll
    for (int r = 0; r < 4; ++r) {
      int i = i0 + w * 16 + quad * 4 + r;
      int j = j0 + t * 16 + colg;
      float e = -ALPHA_C * (float)(j - i) * (acc[t][r] * 0.125f);
      eld[t][r] = e;
      Ob[(size_t)i * LL + j] = e;
    }
  #pragma unroll
  for (int r = 0; r < 4; ++r) {
    float mx = fmaxf(fmaxf(eld[0][r], eld[1][r]), fmaxf(eld[2][r], eld[3][r]));
    #pragma unroll
    for (int d = 1; d < 16; d <<= 1) mx = fmaxf(mx, __shfl_xor(mx, d));
    float s = __expf(eld[0][r]-mx) + __expf(eld[1][r]-mx) + __expf(eld[2][r]-mx) + __expf(eld[3][r]-mx);
    #pragma unroll
    for (int d = 1; d < 16; d <<= 1) s += __shfl_xor(s, d);
    if (colg == 0) {
      int i = i0 + w * 16 + quad * 4 + r;
      size_t idx = (((size_t)bh * LL + i) * 32 + jt) * 2;
      stats[idx] = mx; stats[idx + 1] = s;
    }
  }
}

// ---------------- K3: per-row reduce of tile stats -> (M, S) ----------------
// grid 128 x 256: one thread per row (32768 rows), online combine over 32 tiles.
__global__ __launch_bounds__(256) void k_rowstats(
    const float* __restrict__ stats, float* __restrict__ rowstats)
{
  const int row = blockIdx.x * 256 + threadIdx.x;   // < 32768
  const float* S = stats + (size_t)row * 64;
  float M = -3.0e38f, Ss = 0.f;
  #pragma unroll 8
  for (int k = 0; k < 32; ++k) {
    float m = S[2*k], s = S[2*k+1];
    float nM = fmaxf(M, m);
    Ss = Ss * __expf(M - nM) + s * __expf(m - nM);
    M = nM;
  }
  rowstats[(size_t)row * 2]     = M;
  rowstats[(size_t)row * 2 + 1] = Ss;
}

// ---------------- K4: softmax + pool (in place) + PV (bf16 MFMA), fused --------
// grid (64 i-tiles of 32 rows, 16 bh), 256 thr. Reads logits from the pooled region,
// overwrites with pooled probabilities (left-halo column carried in LDS), accumulates
// outh = pooled @ V with MFMA as j-tiles stream through.
__global__ __launch_bounds__(256) void k_sm_pool_pv(
    float* __restrict__ Pg_all, const float* __restrict__ rowstats,
    const float* __restrict__ vh, float* __restrict__ outh)
{
  const int i0 = blockIdx.x * 32;
  const int bh = blockIdx.y;
  const int b = bh >> 3, h = bh & 7;
  float*       Pg = Pg_all + (size_t)bh * LL * LL;
  const float* V  = vh     + (size_t)bh * LL * 64;

  __shared__ float pL[32][68];       // [row][0]=left halo, [1..64]=tile, [65]=right halo
  __shared__ float Mrow[32], invS[32], leftp[32];
  __shared__ short Asm[32 * 64];     // pooled bf16, A[m=i][k=j]
  __shared__ short Bsm[64 * 64];     // V bf16, B^T[n=d][k=j]

  const int tid = threadIdx.x;
  const int lane = tid & 63, wv = tid >> 6;
  const int wr = wv & 1, wd = wv >> 1;

  if (tid < 32) {
    float2 ms = *(const float2*)&rowstats[((size_t)bh * LL + i0 + tid) * 2];
    Mrow[tid] = ms.x; invS[tid] = 1.0f / ms.y; leftp[tid] = 0.f;
  }
  __syncthreads();

  f32x4 acc[2];
  acc[0][0]=0.f;acc[0][1]=0.f;acc[0][2]=0.f;acc[0][3]=0.f;
  acc[1][0]=0.f;acc[1][1]=0.f;acc[1][2]=0.f;acc[1][3]=0.f;

  const int prow = tid >> 3, pc8 = (tid & 7) * 8;
  const int vk = tid >> 4, vd = (tid & 15) * 4;

  for (int j0 = 0; j0 < LL; j0 += 64) {
    // phase 1: load logits -> p = exp(x-M)/S into pL; halos; stage V tile
    const float Mr = Mrow[prow], iS = invS[prow];
    #pragma unroll
    for (int it = 0; it < 2; ++it) {
      float4 x = *(const float4*)&Pg[(size_t)(i0 + prow) * LL + j0 + pc8 + it * 4];
      int c = 1 + pc8 + it * 4;
      pL[prow][c+0] = __expf(x.x - Mr) * iS;
      pL[prow][c+1] = __expf(x.y - Mr) * iS;
      pL[prow][c+2] = __expf(x.z - Mr) * iS;
      pL[prow][c+3] = __expf(x.w - Mr) * iS;
    }
    if (tid < 32) {
      pL[tid][0] = leftp[tid];
      int j = j0 + 64;
      pL[tid][65] = (j < LL) ? __expf(Pg[(size_t)(i0 + tid) * LL + j] - Mrow[tid]) * invS[tid] : 0.f;
    }
    #pragma unroll
    for (int it = 0; it < 4; ++it) {
      int kk = vk + it * 16;
      float4 a = *(const float4*)&V[(size_t)(j0 + kk) * 64 + vd];
      Bsm[(vd + 0) * 64 + kk] = f2bf(a.x);
      Bsm[(vd + 1) * 64 + kk] = f2bf(a.y);
      Bsm[(vd + 2) * 64 + kk] = f2bf(a.z);
      Bsm[(vd + 3) * 64 + kk] = f2bf(a.w);
    }
    __syncthreads();

    // phase 2: pool, write pooled (in place), build bf16 A tile; carry left halo
    #pragma unroll
    for (int it = 0; it < 2; ++it) {
      float4 o;
      int cc = pc8 + it * 4;
      float p0 = (pL[prow][cc+0] + pL[prow][cc+1] + pL[prow][cc+2]) * (1.0f/3.0f);
      float p1 = (pL[prow][cc+1] + pL[prow][cc+2] + pL[prow][cc+3]) * (1.0f/3.0f);
      float p2 = (pL[prow][cc+2] + pL[prow][cc+3] + pL[prow][cc+4]) * (1.0f/3.0f);
      float p3 = (pL[prow][cc+3] + pL[prow][cc+4] + pL[prow][cc+5]) * (1.0f/3.0f);
      o.x = p0; o.y = p1; o.z = p2; o.w = p3;
      *(float4*)&Pg[(size_t)(i0 + prow) * LL + j0 + cc] = o;
      *(unsigned*)&Asm[prow * 64 + cc]     = pack2(f2bf(p0), f2bf(p1));
      *(unsigned*)&Asm[prow * 64 + cc + 2] = pack2(f2bf(p2), f2bf(p3));
    }
    if (tid < 32) leftp[tid] = pL[tid][64];
    __syncthreads();

    // phase 3: MFMA accumulate
    const int ka = ((lane >> 4) << 3);
    #pragma unroll
    for (int ch = 0; ch < 2; ++ch) {
      bf16x8 af = *(const bf16x8*)&Asm[(wr * 16 + (lane & 15)) * 64 + ka + ch * 32];
      #pragma unroll
      for (int t = 0; t < 2; ++t) {
        bf16x8 bfv = *(const bf16x8*)&Bsm[((wd * 2 + t) * 16 + (lane & 15)) * 64 + ka + ch * 32];
        acc[t] = __builtin_amdgcn_mfma_f32_16x16x32_bf16(af, bfv, acc[t], 0, 0, 0);
      }
    }
    __syncthreads();
  }

  const int quad = lane >> 4, colg = lane & 15;
  #pragma unroll
  for (int t = 0; t < 2; ++t)
    #pragma unroll
    for (int r = 0; r < 4; ++r) {
      int i = i0 + wr * 16 + quad * 4 + r;
      int d = (wd * 2 + t) * 16 + colg;
      outh[((size_t)b * LL + i) * 512 + h * 64 + d] = acc[t][r];
    }
}

// ---------------- K5: fc = out_h @ w_fc^T  (bf16 MFMA) ----------------
__global__ __launch_bounds__(256) void k_fc(
    const float* __restrict__ outh, const float* __restrict__ wfc, float* __restrict__ fcout)
{
  const int n0 = blockIdx.x * 64;
  const int m0 = blockIdx.y * 64;
  __shared__ short Asm[64 * 64];
  __shared__ short Bsm[64 * 64];
  const int tid = threadIdx.x;
  const int lane = tid & 63, w = tid >> 6;

  f32x4 acc[4];
  #pragma unroll
  for (int t = 0; t < 4; ++t) { acc[t][0]=0.f; acc[t][1]=0.f; acc[t][2]=0.f; acc[t][3]=0.f; }

  const int am = tid >> 2, ak = tid & 3;
  for (int k0 = 0; k0 < 512; k0 += 64) {
    #pragma unroll
    for (int it = 0; it < 4; ++it) {
      int kv = ak + 4 * it;
      float4 a = *(const float4*)&outh[(size_t)(m0 + am) * 512 + k0 + kv * 4];
      *(unsigned*)&Asm[am * 64 + kv * 4]     = pack2(f2bf(a.x), f2bf(a.y));
      *(unsigned*)&Asm[am * 64 + kv * 4 + 2] = pack2(f2bf(a.z), f2bf(a.w));
      float4 b = *(const float4*)&wfc[(size_t)(n0 + am) * 512 + k0 + kv * 4];
      *(unsigned*)&Bsm[am * 64 + kv * 4]     = pack2(f2bf(b.x), f2bf(b.y));
      *(unsigned*)&Bsm[am * 64 + kv * 4 + 2] = pack2(f2bf(b.z), f2bf(b.w));
    }
    __syncthreads();
    #pragma unroll
    for (int sub = 0; sub < 64; sub += 32) {
      int krow = sub + ((lane >> 4) << 3);
      bf16x8 af = *(const bf16x8*)&Asm[(w * 16 + (lane & 15)) * 64 + krow];
      #pragma unroll
      for (int t = 0; t < 4; ++t) {
        bf16x8 bfv = *(const bf16x8*)&Bsm[(t * 16 + (lane & 15)) * 64 + krow];
        acc[t] = __builtin_amdgcn_mfma_f32_16x16x32_bf16(af, bfv, acc[t], 0, 0, 0);
      }
    }
    __syncthreads();
  }
  const int q4 = lane >> 4, col = lane & 15;
  #pragma unroll
  for (int t = 0; t < 4; ++t)
    #pragma unroll
    for (int r = 0; r < 4; ++r) {
      int m = m0 + w * 16 + q4 * 4 + r;
      fcout[(size_t)m * 512 + n0 + t * 16 + col] = acc[t][r];
    }
}

// ---------------- K6: residual + LayerNorm ----------------
__global__ __launch_bounds__(256) void k_ln(
    const float* __restrict__ fcout, const float* __restrict__ resid,
    const float* __restrict__ gamma, const float* __restrict__ beta,
    float* __restrict__ out)
{
  const size_t row = blockIdx.x;
  const int tid = threadIdx.x;
  __shared__ float red[256];

  float x0 = fcout[row * 512 + tid]       + resid[row * 512 + tid];
  float x1 = fcout[row * 512 + 256 + tid] + resid[row * 512 + 256 + tid];

  red[tid] = x0 + x1; __syncthreads();
  for (int off = 128; off > 0; off >>= 1) {
    if (tid < off) red[tid] += red[tid + off];
    __syncthreads();
  }
  const float mu = red[0] * (1.0f / 512.0f); __syncthreads();

  float d0 = x0 - mu, d1 = x1 - mu;
  red[tid] = d0 * d0 + d1 * d1; __syncthreads();
  for (int off = 128; off > 0; off >>= 1) {
    if (tid < off) red[tid] += red[tid + off];
    __syncthreads();
  }
  const float var = red[0] * (1.0f / 512.0f);
  const float rstd = 1.0f / sqrtf(var + 1e-6f);

  out[row * 512 + tid]       = d0 * rstd * gamma[tid]       + beta[tid];
  out[row * 512 + 256 + tid] = d1 * rstd * gamma[tid + 256] + beta[tid + 256];
}

// ---------------- launch ----------------
extern "C" void kernel_launch(void* const* d_in, const int* in_sizes, int n_in,
                              void* d_out, int out_size, void* d_ws, size_t ws_size,
                              hipStream_t stream)
{
  const float* q     = (const float*)d_in[0];
  const float* k     = (const float*)d_in[1];
  const float* v     = (const float*)d_in[2];
  const float* wq    = (const float*)d_in[3];
  const float* wk    = (const float*)d_in[4];
  const float* wv    = (const float*)d_in[5];
  const float* wfc   = (const float*)d_in[6];
  const float* gamma = (const float*)d_in[7];
  const float* beta  = (const float*)d_in[8];

  float* out    = (float*)d_out;
  float* pooled = out + OUT0;            // output 1; doubles as logits scratch

  float* wsf      = (float*)d_ws;        // 32 MB total
  float* qh       = wsf;                 // 8 MB  (dead after k_qk -> rowstats live here)
  float* kh       = wsf + QH_ELEMS;      // 8 MB  (dead after k_qk -> fcout lives here)
  float* vh       = wsf + 2 * QH_ELEMS;  // 8 MB
  float* stats    = wsf + 3 * QH_ELEMS;  // 8 MB: [32768 rows][32 tiles][m,s]; dead after
  float* outh     = wsf + 3 * QH_ELEMS;  //       k_rowstats -> PV output reuses region
  float* rowstats = qh;                  // 256 KB: [32768][M,S]
  float* fcout    = kh;

  k_proj      <<<dim3(24, 64),     256, 0, stream>>>(q, k, v, wq, wk, wv, qh, kh, vh);
  k_qk        <<<dim3(32, 32, 16), 256, 0, stream>>>(qh, kh, pooled, stats);
  k_rowstats  <<<dim3(128),        256, 0, stream>>>(stats, rowstats);
  k_sm_pool_pv<<<dim3(64, 16),     256, 0, stream>>>(pooled, rowstats, vh, outh);
  k_fc        <<<dim3(8, 64),      256, 0, stream>>>(outh, wfc, fcout);
  k_ln        <<<dim3(4096),       256, 0, stream>>>(fcout, q, gamma, beta, out);
}